// Round 6
// baseline (130.825 us; speedup 1.0000x reference)
//
#include <hip/hip_runtime.h>

// Complex magnitude max-pool 2x2 (stride 2, VALID), NHWC.
// Input: x_real, x_imag [8,512,512,32] f32. Output: [8,256,256,32,2] f32.
// Identity: mag*cos(atan2(im,re)) == re, mag*sin(...) == im, so the op is an
// argmax(|x|)-gather of (re,im) over each 2x2 window.
// Argmax key computed bit-exactly like numpy (rounded mul/mul/add + IEEE
// sqrt); first-occurrence tie-break reproduced exactly (see combine logic).
//
// R5: wave-contiguous remap. item = (b, ho, input-w, c4): every wave load
// instruction covers 1KB fully contiguous (was 50%-dense 128B chunks at
// 256B stride), every store is one 16B/lane, wave-contiguous 1KB (was 2
// half-dense stores). Horizontal 2x2 combine via __shfl_xor(8).

typedef float f32x4 __attribute__((ext_vector_type(4)));

constexpr int B  = 8;
constexpr int H  = 512;
constexpr int W  = 512;
constexpr int C  = 32;
constexpr int Ho = H / 2;
constexpr int Wo = W / 2;
// item = (b, ho, w, c4):  c4 = g&7, w = (g>>3)&511, ho = (g>>12)&255, b = g>>20
constexpr long TOTAL = (long)B * Ho * W * (C / 4);     // 8,388,608
constexpr int  BLOCK = 256;
constexpr int  GRID  = 2048;
constexpr int  ITERS = (int)(TOTAL / ((long)BLOCK * GRID));   // 16, exact
static_assert((long)BLOCK * GRID * ITERS == TOTAL, "exact tiling");

__device__ __forceinline__ float ref_mag(float r, float i) {
  return __fsqrt_rn(__fadd_rn(__fmul_rn(r, r), __fmul_rn(i, i)));
}

struct Frag { f32x4 r0, r1, i0, i1; };   // rows h, h+1 of own (w, c4) column

__device__ __forceinline__ void load_frag(const float* __restrict__ xr,
                                          const float* __restrict__ xi,
                                          long g, Frag& f) {
  const int c4 = (int)(g & 7);
  const int w  = (int)((g >> 3) & (W - 1));
  const int ho = (int)((g >> 12) & (Ho - 1));
  const int b  = (int)(g >> 20);
  const long base0 = (((long)(b * H + 2 * ho) * W) + w) * C + c4 * 4;
  const long base1 = base0 + (long)W * C;
  f.r0 = *(const f32x4*)(xr + base0);
  f.r1 = *(const f32x4*)(xr + base1);
  f.i0 = *(const f32x4*)(xi + base0);
  f.i1 = *(const f32x4*)(xi + base1);
}

__device__ __forceinline__ void compute_store(float* __restrict__ out,
                                              long g, const Frag& f) {
  const int c4 = (int)(g & 7);
  const int w  = (int)((g >> 3) & (W - 1));
  const int ho = (int)((g >> 12) & (Ho - 1));
  const int b  = (int)(g >> 20);
  const int parity = w & 1;        // 0: window cols k0/k2, 1: k1/k3
  const int wo = w >> 1;

  // Vertical reduce (own column, rows h vs h+1). Strict '>' keeps row h on
  // ties == keeps the smaller window index.
  float vm[4], vre[4], vim[4];
  int vrow = 0;                    // bit j: picked row h+1 for channel j
#pragma unroll
  for (int j = 0; j < 4; ++j) {
    const float m0 = ref_mag(f.r0[j], f.i0[j]);
    const float m1 = ref_mag(f.r1[j], f.i1[j]);
    const bool p1 = (m1 > m0);
    vm[j]  = p1 ? m1 : m0;
    vre[j] = p1 ? f.r1[j] : f.r0[j];
    vim[j] = p1 ? f.i1[j] : f.i0[j];
    vrow  |= (int)p1 << j;
  }

  // Exchange with partner lane (same c4, adjacent w): lane ^ 8.
  float pm[4], pre[4], pim[4];
#pragma unroll
  for (int j = 0; j < 4; ++j) {
    pm[j]  = __shfl_xor(vm[j], 8);
    pre[j] = __shfl_xor(vre[j], 8);
    pim[j] = __shfl_xor(vim[j], 8);
  }
  const int prow = __shfl_xor(vrow, 8);

  // Horizontal combine. E = even-w side (indices {0,2}), O = odd ({1,3}).
  // jnp.argmax first-occurrence: take O iff mO>mE, or mO==mE && Eidx==2 &&
  // Oidx==1 (the only tie case where O's index is smaller).
  float fre[4], fim[4];
#pragma unroll
  for (int j = 0; j < 4; ++j) {
    const float Em  = parity ? pm[j]  : vm[j];
    const float Ere = parity ? pre[j] : vre[j];
    const float Eim = parity ? pim[j] : vim[j];
    const int   Er  = (parity ? prow : vrow) >> j & 1;
    const float Om  = parity ? vm[j]  : pm[j];
    const float Ore = parity ? vre[j] : pre[j];
    const float Oim = parity ? vim[j] : pim[j];
    const int   Or  = (parity ? vrow : prow) >> j & 1;
    const bool chooseO = (Om > Em) || ((Om == Em) && Er && !Or);
    fre[j] = chooseO ? Ore : Ere;
    fim[j] = chooseO ? Oim : Eim;
  }

  // Store: even lane writes channels {0,1}, odd lane {2,3} of the c4 group.
  // One 16B store per lane; wave covers 1KB contiguous.
  const long obase =
      ((((long)(b * Ho + ho) * Wo) + wo) * C + c4 * 4) * 2 + parity * 4;
  f32x4 o;
  o.x = parity ? fre[2] : fre[0];
  o.y = parity ? fim[2] : fim[0];
  o.z = parity ? fre[3] : fre[1];
  o.w = parity ? fim[3] : fim[1];
  *(f32x4*)(out + obase) = o;
}

__global__ __launch_bounds__(BLOCK) void cmaxpool_kernel(
    const float* __restrict__ xr,
    const float* __restrict__ xi,
    float* __restrict__ out) {
  const long stride = (long)GRID * BLOCK;
  long g = (long)blockIdx.x * BLOCK + threadIdx.x;

  Frag fa, fb;
  load_frag(xr, xi, g, fa);
#pragma unroll
  for (int it = 0; it < ITERS; it += 2) {
    if (it + 1 < ITERS) load_frag(xr, xi, g + stride, fb);
    __builtin_amdgcn_sched_barrier(0);   // prefetch issued before consume
    compute_store(out, g, fa);
    if (it + 2 < ITERS) load_frag(xr, xi, g + 2 * stride, fa);
    __builtin_amdgcn_sched_barrier(0);
    if (it + 1 < ITERS) compute_store(out, g + stride, fb);
    g += 2 * stride;
  }
}

extern "C" void kernel_launch(void* const* d_in, const int* in_sizes, int n_in,
                              void* d_out, int out_size, void* d_ws, size_t ws_size,
                              hipStream_t stream) {
  const float* xr = (const float*)d_in[0];
  const float* xi = (const float*)d_in[1];
  float* out = (float*)d_out;
  cmaxpool_kernel<<<GRID, BLOCK, 0, stream>>>(xr, xi, out);
}

// Round 7
// 124.031 us; speedup vs baseline: 1.0548x; 1.0548x over previous
//
#include <hip/hip_runtime.h>

// Complex magnitude max-pool 2x2 (stride 2, VALID), NHWC.
// Input: x_real, x_imag [8,512,512,32] f32. Output: [8,256,256,32,2] f32.
// Identity: mag*cos(atan2(im,re)) == re, mag*sin(...) == im, so the op is an
// argmax(|x|)-gather of (re,im) over each 2x2 window.
// Argmax key computed bit-exactly like numpy (rounded mul/mul/add + IEEE
// sqrt); first-occurrence tie-break reproduced exactly (see combine logic).
//
// R5: wave-contiguous remap; loads 1KB/wave-instr, stores 1KB/wave-instr.
// R6: + non-temporal stores. Output is never re-read; NT avoids L2/L3
// write-allocate so the 134MB output stream stops evicting the L3-resident
// input. Safe now (unlike R3) because each wave store covers full 128B
// lines — no partial-line write amplification.

typedef float f32x4 __attribute__((ext_vector_type(4)));

constexpr int B  = 8;
constexpr int H  = 512;
constexpr int W  = 512;
constexpr int C  = 32;
constexpr int Ho = H / 2;
constexpr int Wo = W / 2;
// item = (b, ho, w, c4):  c4 = g&7, w = (g>>3)&511, ho = (g>>12)&255, b = g>>20
constexpr long TOTAL = (long)B * Ho * W * (C / 4);     // 8,388,608
constexpr int  BLOCK = 256;
constexpr int  GRID  = 2048;
constexpr int  ITERS = (int)(TOTAL / ((long)BLOCK * GRID));   // 16, exact
static_assert((long)BLOCK * GRID * ITERS == TOTAL, "exact tiling");

__device__ __forceinline__ float ref_mag(float r, float i) {
  return __fsqrt_rn(__fadd_rn(__fmul_rn(r, r), __fmul_rn(i, i)));
}

struct Frag { f32x4 r0, r1, i0, i1; };   // rows h, h+1 of own (w, c4) column

__device__ __forceinline__ void load_frag(const float* __restrict__ xr,
                                          const float* __restrict__ xi,
                                          long g, Frag& f) {
  const int c4 = (int)(g & 7);
  const int w  = (int)((g >> 3) & (W - 1));
  const int ho = (int)((g >> 12) & (Ho - 1));
  const int b  = (int)(g >> 20);
  const long base0 = (((long)(b * H + 2 * ho) * W) + w) * C + c4 * 4;
  const long base1 = base0 + (long)W * C;
  f.r0 = *(const f32x4*)(xr + base0);
  f.r1 = *(const f32x4*)(xr + base1);
  f.i0 = *(const f32x4*)(xi + base0);
  f.i1 = *(const f32x4*)(xi + base1);
}

__device__ __forceinline__ void compute_store(float* __restrict__ out,
                                              long g, const Frag& f) {
  const int c4 = (int)(g & 7);
  const int w  = (int)((g >> 3) & (W - 1));
  const int ho = (int)((g >> 12) & (Ho - 1));
  const int b  = (int)(g >> 20);
  const int parity = w & 1;        // 0: window cols k0/k2, 1: k1/k3
  const int wo = w >> 1;

  // Vertical reduce (own column, rows h vs h+1). Strict '>' keeps row h on
  // ties == keeps the smaller window index.
  float vm[4], vre[4], vim[4];
  int vrow = 0;                    // bit j: picked row h+1 for channel j
#pragma unroll
  for (int j = 0; j < 4; ++j) {
    const float m0 = ref_mag(f.r0[j], f.i0[j]);
    const float m1 = ref_mag(f.r1[j], f.i1[j]);
    const bool p1 = (m1 > m0);
    vm[j]  = p1 ? m1 : m0;
    vre[j] = p1 ? f.r1[j] : f.r0[j];
    vim[j] = p1 ? f.i1[j] : f.i0[j];
    vrow  |= (int)p1 << j;
  }

  // Exchange with partner lane (same c4, adjacent w): lane ^ 8.
  float pm[4], pre[4], pim[4];
#pragma unroll
  for (int j = 0; j < 4; ++j) {
    pm[j]  = __shfl_xor(vm[j], 8);
    pre[j] = __shfl_xor(vre[j], 8);
    pim[j] = __shfl_xor(vim[j], 8);
  }
  const int prow = __shfl_xor(vrow, 8);

  // Horizontal combine. E = even-w side (indices {0,2}), O = odd ({1,3}).
  // jnp.argmax first-occurrence: take O iff mO>mE, or mO==mE && Eidx==2 &&
  // Oidx==1 (the only tie case where O's index is smaller).
  float fre[4], fim[4];
#pragma unroll
  for (int j = 0; j < 4; ++j) {
    const float Em  = parity ? pm[j]  : vm[j];
    const float Ere = parity ? pre[j] : vre[j];
    const float Eim = parity ? pim[j] : vim[j];
    const int   Er  = (parity ? prow : vrow) >> j & 1;
    const float Om  = parity ? vm[j]  : pm[j];
    const float Ore = parity ? vre[j] : pre[j];
    const float Oim = parity ? vim[j] : pim[j];
    const int   Or  = (parity ? vrow : prow) >> j & 1;
    const bool chooseO = (Om > Em) || ((Om == Em) && Er && !Or);
    fre[j] = chooseO ? Ore : Ere;
    fim[j] = chooseO ? Oim : Eim;
  }

  // Store: even lane writes channels {0,1}, odd lane {2,3} of the c4 group.
  // One 16B NT store per lane; wave covers 1KB contiguous (full lines).
  const long obase =
      ((((long)(b * Ho + ho) * Wo) + wo) * C + c4 * 4) * 2 + parity * 4;
  f32x4 o;
  o.x = parity ? fre[2] : fre[0];
  o.y = parity ? fim[2] : fim[0];
  o.z = parity ? fre[3] : fre[1];
  o.w = parity ? fim[3] : fim[1];
  __builtin_nontemporal_store(o, (f32x4*)(out + obase));
}

__global__ __launch_bounds__(BLOCK) void cmaxpool_kernel(
    const float* __restrict__ xr,
    const float* __restrict__ xi,
    float* __restrict__ out) {
  const long stride = (long)GRID * BLOCK;
  long g = (long)blockIdx.x * BLOCK + threadIdx.x;

  Frag fa, fb;
  load_frag(xr, xi, g, fa);
#pragma unroll
  for (int it = 0; it < ITERS; it += 2) {
    if (it + 1 < ITERS) load_frag(xr, xi, g + stride, fb);
    __builtin_amdgcn_sched_barrier(0);   // prefetch issued before consume
    compute_store(out, g, fa);
    if (it + 2 < ITERS) load_frag(xr, xi, g + 2 * stride, fa);
    __builtin_amdgcn_sched_barrier(0);
    if (it + 1 < ITERS) compute_store(out, g + stride, fb);
    g += 2 * stride;
  }
}

extern "C" void kernel_launch(void* const* d_in, const int* in_sizes, int n_in,
                              void* d_out, int out_size, void* d_ws, size_t ws_size,
                              hipStream_t stream) {
  const float* xr = (const float*)d_in[0];
  const float* xi = (const float*)d_in[1];
  float* out = (float*)d_out;
  cmaxpool_kernel<<<GRID, BLOCK, 0, stream>>>(xr, xi, out);
}